// Round 3
// baseline (1057.275 us; speedup 1.0000x reference)
//
#include <hip/hip_runtime.h>
#include <math.h>

// ---------------- problem constants ----------------
#define NLD 16      // degrees l = 0..15
#define NSX 136     // # (l, m>=0) pairs = sum(l+1)
#define NS  256     // # (l, m) pairs full = NL^2
#define KG  24      // kernel grid points
#define FI  64
#define FO  128
#define NB  8
#define NJI 64      // 2*B_IN
#define NJO 32      // 2*B_OUT
#define NZ  2856    // # (l, m>=0, n) triples = sum (l+1)(2l+1)
#define SCALING 0.07216878364870323  // 1/sqrt(24*64*16^3/32^3) = 1/sqrt(192)

// base offset of degree l in the (l,m>=0,n) l-major packing
__device__ const int BASE[17] = {0,1,7,22,50,95,161,252,372,525,715,946,
                                 1222,1547,1925,2360,2856};
// compile-time copy for unrolled loops (folds to immediates)
__device__ constexpr int CBASE[17] = {0,1,7,22,50,95,161,252,372,525,715,946,
                                      1222,1547,1925,2360,2856};

__device__ const double FACT[33] = {
  1.0,1.0,2.0,6.0,24.0,120.0,720.0,5040.0,40320.0,362880.0,3628800.0,
  39916800.0,479001600.0,6227020800.0,87178291200.0,1307674368000.0,
  20922789888000.0,355687428096000.0,6402373705728000.0,121645100408832000.0,
  2432902008176640000.0,51090942171709440000.0,1124000727777607680000.0,
  25852016738884976640000.0,620448401733239439360000.0,
  15511210043330985984000000.0,403291461126605635584000000.0,
  10888869450418352160768000000.0,304888344611713860501504000000.0,
  8841761993739701954543616000000.0,265252859812191058636308480000000.0,
  8222838654177922817725562880000000.0,263130836933693530167218012160000000.0};

// Wigner small-d d^l_{m,n}(beta), double precision, matches reference formula
__device__ double wig_d(int l, int m, int n, double beta) {
  double cb = cos(0.5 * beta), sb = sin(0.5 * beta);
  int smin = max(0, n - m), smax = min(l + n, l - m);
  double pref = sqrt(FACT[l + m] * FACT[l - m] * FACT[l + n] * FACT[l - n]);
  int ec = 2 * l + n - m - 2 * smin;   // >= 0
  int es = m - n + 2 * smin;           // >= 0
  double p = 1.0;
  for (int t = 0; t < ec; ++t) p *= cb;
  for (int t = 0; t < es; ++t) p *= sb;
  double r = (sb * sb) / (cb * cb);
  double out = 0.0;
  for (int s = smin; s <= smax; ++s) {
    double coef = 1.0 / (FACT[l + n - s] * FACT[s] * FACT[m - n + s] * FACT[l - m - s]);
    if ((m - n + s) & 1) coef = -coef;
    out += coef * p;
    p *= r;
  }
  return pref * out;
}

// ---------------- K0: all transform constants (fp64 -> fp32) ----------------
__global__ __launch_bounds__(256) void k_const(float* __restrict__ WD,
                                               float2* __restrict__ YK,
                                               float* __restrict__ Dp) {
  int idx = blockIdx.x * 256 + threadIdx.x;
  if (idx < NSX * NJI) {
    int sx = idx / NJI, j = idx % NJI;
    int l = 0; while ((l + 1) * (l + 2) / 2 <= sx) ++l;
    int m = sx - l * (l + 1) / 2;
    double beta = (j + 0.5) * M_PI / NJI;
    double s = 0.0;
    for (int k = 0; k < 32; ++k)
      s += sin((2.0 * j + 1.0) * (2.0 * k + 1.0) * M_PI / 128.0) / (2.0 * k + 1.0);
    double w = (2.0 / 32.0) * sin(beta) * s * (2.0 * M_PI / 64.0);
    WD[sx * NJI + j] = (float)(w * wig_d(l, m, 0, beta));
    return;
  }
  idx -= NSX * NJI;
  if (idx < NS * KG) {
    int sidx = idx / KG, k = idx % KG;
    int l = 0; while ((l + 1) * (l + 1) <= sidx) ++l;
    int m = sidx - l * l - l;                       // signed m
    double gb = (double)(k / 8 + 1) * (M_PI / 8.0) / 3.0;
    double ga = (double)(k % 8) * (2.0 * M_PI / 8.0);
    double d = wig_d(l, m, 0, gb) * SCALING;
    double sn, c; sincos((double)m * ga, &sn, &c);
    YK[sidx * KG + k] = make_float2((float)(d * c), (float)(-d * sn)); // e^{-i m a}
    return;
  }
  idx -= NS * KG;
  if (idx < NJO * NZ) {
    int j = idx / NZ, z = idx % NZ;
    int l = 0; while (BASE[l + 1] <= z) ++l;
    int rem = z - BASE[l];
    int m = rem / (2 * l + 1);
    int n = rem % (2 * l + 1) - l;                  // signed n
    double beta = (j + 0.5) * M_PI / NJO;
    Dp[j * NZ + z] = (float)((2 * l + 1) * wig_d(l, m, n, beta));
  }
}

// ---------------- K1: S2 forward transform ----------------
__global__ __launch_bounds__(256) void k_s2fft(const float* __restrict__ x,
                                               const float* __restrict__ WD,
                                               float2* __restrict__ X) {
  __shared__ float  xl[NJI * NJI];   // [j][a] 16 KB
  __shared__ float2 tw[NJI];
  __shared__ float2 xf[NJI * 16];    // [j][m] 8 KB
  __shared__ float2 fx[NSX];
  int t = threadIdx.x;
  int b = blockIdx.x >> 6, f = blockIdx.x & 63;
  const float* xp = x + (size_t)(b * FI + f) * (NJI * NJI);
  for (int r = 0; r < 16; ++r) xl[t + 256 * r] = xp[t + 256 * r];
  if (t < NJI) {
    double s_, c_; sincos(2.0 * M_PI * t / NJI, &s_, &c_);
    tw[t] = make_float2((float)c_, (float)s_);
  }
  __syncthreads();
  for (int r = 0; r < 4; ++r) {
    int oi = t + 256 * r;            // oi = j*16 + m
    int j = oi >> 4, m = oi & 15;
    float re = 0.f, im = 0.f;
    const float* row = xl + j * NJI;
    for (int a = 0; a < NJI; ++a) {
      float2 w = tw[(m * a) & 63];
      float v = row[a];
      re += v * w.x; im -= v * w.y;  // e^{-2pi i m a / 64}
    }
    xf[oi] = make_float2(re, im);
  }
  __syncthreads();
  if (t < NSX) {
    int l = 0; while ((l + 1) * (l + 2) / 2 <= t) ++l;
    int m = t - l * (l + 1) / 2;
    float re = 0.f, im = 0.f;
    const float* wrow = WD + t * NJI;
    for (int j = 0; j < NJI; ++j) {
      float wv = wrow[j];
      float2 v = xf[j * 16 + m];
      re += wv * v.x; im += wv * v.y;
    }
    fx[t] = make_float2(re, im);
  }
  __syncthreads();
  {
    int l = t >> 4, m = t & 15;
    float2 v = make_float2(0.f, 0.f);
    if (m <= l) v = fx[l * (l + 1) / 2 + m];
    X[((size_t)t * NB + b) * FI + f] = v;           // row t = l*16+m (padded)
  }
}

// ---------------- K2: kernel spherical transform ----------------
__global__ __launch_bounds__(256) void k_ytrans(const float* __restrict__ kern,
                                                const float2* __restrict__ YK,
                                                float2* __restrict__ Y) {
  __shared__ float  kl[FO][KG + 1];
  __shared__ float2 ykl[32][KG];
  int t = threadIdx.x;
  int i = blockIdx.x & 63, st = blockIdx.x >> 6;   // s-tile of 32
  int s0 = st * 32;
  for (int r = 0; r < 12; ++r) {
    int fid = t + 256 * r;                          // 3072 floats
    kl[fid / KG][fid % KG] = kern[(size_t)i * FO * KG + fid];
  }
  for (int r = 0; r < 3; ++r) {
    int fid = t + 256 * r;                          // 768 float2
    ykl[fid / KG][fid % KG] = YK[(s0 + fid / KG) * KG + fid % KG];
  }
  __syncthreads();
  int o = t & 127, sh = t >> 7;
  float kr[KG];
  #pragma unroll
  for (int k = 0; k < KG; ++k) kr[k] = kl[o][k];
  for (int ss = sh; ss < 32; ss += 2) {
    float re = 0.f, im = 0.f;
    #pragma unroll
    for (int k = 0; k < KG; ++k) {
      float2 yv = ykl[ss][k];
      re += kr[k] * yv.x; im += kr[k] * yv.y;
    }
    Y[((size_t)(s0 + ss) * FI + i) * FO + o] = make_float2(re, im);
  }
}

// ---------------- K3: block-diagonal spectral matmul ----------------
__global__ __launch_bounds__(256) void k_zmm(const float2* __restrict__ X,
                                             const float2* __restrict__ Y,
                                             float2* __restrict__ Z) {
  __shared__ float2 xs[256 * 16];    // [row=l*16+m][ii] 32 KB
  int t = threadIdx.x;
  int b  = blockIdx.x >> 6;
  int ot = (blockIdx.x >> 4) & 3;
  int st = blockIdx.x & 15;          // s-tile of 16
  int s0 = st * 16;
  int o  = ot * 32 + (t & 31);
  int sg = t >> 5;                   // 0..7
  int sq[2] = { s0 + sg, s0 + sg + 8 };
  int lq[2], nq[2];
  #pragma unroll
  for (int q = 0; q < 2; ++q) {
    int s = sq[q];
    int l = 0; while ((l + 1) * (l + 1) <= s) ++l;
    lq[q] = l; nq[q] = s - l * l;    // = n + l
  }
  float2 acc[2][16];
  #pragma unroll
  for (int q = 0; q < 2; ++q)
    #pragma unroll
    for (int m = 0; m < 16; ++m) acc[q][m] = make_float2(0.f, 0.f);

  for (int ic = 0; ic < 4; ++ic) {
    __syncthreads();
    for (int r = 0; r < 16; ++r) {
      int fid = t + 256 * r;         // 4096 float2
      int row = fid >> 4, ii = fid & 15;
      xs[fid] = X[((size_t)row * NB + b) * FI + ic * 16 + ii];
    }
    __syncthreads();
    for (int ii = 0; ii < 16; ++ii) {
      int i = ic * 16 + ii;
      #pragma unroll
      for (int q = 0; q < 2; ++q) {
        float2 yv = Y[((size_t)sq[q] * FI + i) * FO + o];
        const float2* xrow = xs + (lq[q] * 16) * 16 + ii;
        #pragma unroll
        for (int m = 0; m < 16; ++m) {
          float2 xv = xrow[m * 16];
          acc[q][m].x += xv.x * yv.x + xv.y * yv.y;   // X * conj(Y)
          acc[q][m].y += xv.y * yv.x - xv.x * yv.y;
        }
      }
    }
  }
  size_t zb = ((size_t)b * FO + o) * NZ;
  for (int q = 0; q < 2; ++q) {
    int l = lq[q];
    for (int m = 0; m <= l; ++m) {
      int zidx = BASE[l] + m * (2 * l + 1) + nq[q];
      Z[zb + zidx] = acc[q][m];
    }
  }
}

// ---------------- K4: SO(3) synthesis (v2: block-cooperative per j) ----------------
// one block per (b,o). Per j: Dp row staged to LDS (coalesced; kills the
// scattered-global latency chain), then block-wide T (496), U (512), f (1024)
// with 3 barriers. T-phase l-loop fully unrolled, branchless predicate.
//   T[m,n] = sum_l Dp[j][zidx]*Z[zidx]          (m=0..15, n=-15..15)
//   U[m,g] = sum_n T[m,n] e^{+2pi i n g/32}
//   f[a,g] = Re U[0,g] + 2 sum_{m>=1} (cos(2pi m a/32) ReU - sin ImU)
__global__ __launch_bounds__(256) void k_synth(const float2* __restrict__ Z,
                                               const float* __restrict__ Dp,
                                               float* __restrict__ out) {
  __shared__ float2 zs[NZ];          // 22.8 KB
  __shared__ float  dpl[NZ];         // 11.4 KB
  __shared__ float2 tt[496];         // 4 KB (block-shared now)
  __shared__ float2 uu[512];         // 4 KB
  __shared__ float2 tws[32];
  int t = threadIdx.x;
  int b = blockIdx.x >> 7, o = blockIdx.x & 127;
  const float2* zg = Z + ((size_t)b * FO + o) * NZ;
  for (int r = 0; r < 12; ++r) {
    int fid = t + 256 * r;
    if (fid < NZ) zs[fid] = zg[fid];
  }
  if (t < 32) {
    double s_, c_; sincos(2.0 * M_PI * t / 32.0, &s_, &c_);
    tws[t] = make_float2((float)c_, (float)s_);
  }
  float* outb = out + ((size_t)b * FO + o) * (NJO * NJO * NJO);
  __syncthreads();
  for (int j = 0; j < 32; ++j) {
    // ---- stage Dp row j (coalesced, L2-hot) ----
    const float* dpj = Dp + (size_t)j * NZ;
    for (int r = 0; r < 12; ++r) {
      int fid = t + 256 * r;
      if (fid < NZ) dpl[fid] = dpj[fid];
    }
    __syncthreads();
    // ---- T: block-wide, unrolled l, branchless ----
    #pragma unroll
    for (int k = 0; k < 2; ++k) {
      int p = t + 256 * k;
      if (p < 496) {
        int m = p / 31;
        int n = p % 31 - 15;
        int an = n < 0 ? -n : n;
        int lmin = m > an ? m : an;
        float re = 0.f, im = 0.f;
        #pragma unroll
        for (int l = 0; l < 16; ++l) {
          int idx = CBASE[l] + m * (2 * l + 1) + n + l;
          bool v = (l >= lmin);
          int ix = v ? idx : 0;
          float d = v ? dpl[ix] : 0.f;
          float2 zv = zs[ix];
          re += d * zv.x; im += d * zv.y;
        }
        tt[p] = make_float2(re, im);
      }
    }
    __syncthreads();
    // ---- U: block-wide ----
    #pragma unroll
    for (int k = 0; k < 2; ++k) {
      int oi = t + 256 * k;          // oi = m*32 + g
      int m = oi >> 5, g = oi & 31;
      float ur = 0.f, ui = 0.f;
      int idx = (17 * g) & 31;       // (-15*g) mod 32
      const float2* trow = tt + m * 31;
      #pragma unroll
      for (int n = 0; n < 31; ++n) {
        float2 tv = trow[n];
        float2 wv = tws[idx];
        ur += tv.x * wv.x - tv.y * wv.y;
        ui += tv.x * wv.y + tv.y * wv.x;
        idx = (idx + g) & 31;
      }
      uu[oi] = make_float2(ur, ui);
    }
    __syncthreads();
    // ---- f: block-wide, coalesced store ----
    float* outj = outb + (size_t)j * 1024;
    #pragma unroll
    for (int k = 0; k < 4; ++k) {
      int oi = t + 256 * k;          // oi = a*32 + g
      int a = oi >> 5, g = oi & 31;
      float val = uu[g].x;           // m = 0 term
      #pragma unroll
      for (int m = 1; m < 16; ++m) {
        float2 wv = tws[(m * a) & 31];
        float2 um = uu[m * 32 + g];
        val += 2.f * (wv.x * um.x - wv.y * um.y);
      }
      outj[oi] = val;
    }
    // no barrier needed here: next iter's dpl staging races only with T,
    // which is fenced by the post-stage barrier.
  }
}

// ---------------- launch ----------------
extern "C" void kernel_launch(void* const* d_in, const int* in_sizes, int n_in,
                              void* d_out, int out_size, void* d_ws, size_t ws_size,
                              hipStream_t stream) {
  (void)in_sizes; (void)n_in; (void)out_size; (void)ws_size;
  const float* x    = (const float*)d_in[0];
  const float* kern = (const float*)d_in[1];
  float* out = (float*)d_out;
  float* ws  = (float*)d_ws;
  // workspace layout (float offsets, all 8B-aligned)
  float*  WD = ws;                        // 8704 f
  float2* YK = (float2*)(ws + 8704);      // 6144 f2
  float*  Dp = ws + 20992;                // 91392 f
  float2* X  = (float2*)(ws + 112384);    // 131072 f2
  float2* Y  = (float2*)(ws + 374528);    // 2097152 f2
  float2* Z  = (float2*)(ws + 4568832);   // 2924544 f2  (ends at 41.7 MB)
  hipLaunchKernelGGL(k_const,  dim3(416),  dim3(256), 0, stream, WD, YK, Dp);
  hipLaunchKernelGGL(k_s2fft,  dim3(512),  dim3(256), 0, stream, x, WD, X);
  hipLaunchKernelGGL(k_ytrans, dim3(512),  dim3(256), 0, stream, kern, YK, Y);
  hipLaunchKernelGGL(k_zmm,    dim3(512),  dim3(256), 0, stream, X, Y, Z);
  hipLaunchKernelGGL(k_synth,  dim3(1024), dim3(256), 0, stream, Z, Dp, out);
}

// Round 6
// 498.690 us; speedup vs baseline: 2.1201x; 2.1201x over previous
//
#include <hip/hip_runtime.h>
#include <math.h>

// ---------------- problem constants ----------------
#define NLD 16      // degrees l = 0..15
#define NSX 136     // # (l, m>=0) pairs = sum(l+1)
#define NS  256     // # (l, m) pairs full = NL^2
#define KG  24      // kernel grid points
#define FI  64
#define FO  128
#define NB  8
#define NJI 64      // 2*B_IN
#define NJO 32      // 2*B_OUT
#define NZ  2856    // # (l, m>=0, n) triples = sum (l+1)(2l+1)
#define NQ  496     // # (m>=0, n) pairs = 16*31
#define NBO 1024    // B*FO
#define SCALING 0.07216878364870323  // 1/sqrt(24*64*16^3/32^3) = 1/sqrt(192)

// base offset of degree l in the (l,m>=0,n) l-major packing
__device__ const int BASE[17] = {0,1,7,22,50,95,161,252,372,525,715,946,
                                 1222,1547,1925,2360,2856};

__device__ const double FACT[33] = {
  1.0,1.0,2.0,6.0,24.0,120.0,720.0,5040.0,40320.0,362880.0,3628800.0,
  39916800.0,479001600.0,6227020800.0,87178291200.0,1307674368000.0,
  20922789888000.0,355687428096000.0,6402373705728000.0,121645100408832000.0,
  2432902008176640000.0,51090942171709440000.0,1124000727777607680000.0,
  25852016738884976640000.0,620448401733239439360000.0,
  15511210043330985984000000.0,403291461126605635584000000.0,
  10888869450418352160768000000.0,304888344611713860501504000000.0,
  8841761993739701954543616000000.0,265252859812191058636308480000000.0,
  8222838654177922817725562880000000.0,263130836933693530167218012160000000.0};

// Wigner small-d d^l_{m,n}(beta), double precision, matches reference formula
__device__ double wig_d(int l, int m, int n, double beta) {
  double cb = cos(0.5 * beta), sb = sin(0.5 * beta);
  int smin = max(0, n - m), smax = min(l + n, l - m);
  double pref = sqrt(FACT[l + m] * FACT[l - m] * FACT[l + n] * FACT[l - n]);
  int ec = 2 * l + n - m - 2 * smin;   // >= 0
  int es = m - n + 2 * smin;           // >= 0
  double p = 1.0;
  for (int t = 0; t < ec; ++t) p *= cb;
  for (int t = 0; t < es; ++t) p *= sb;
  double r = (sb * sb) / (cb * cb);
  double out = 0.0;
  for (int s = smin; s <= smax; ++s) {
    double coef = 1.0 / (FACT[l + n - s] * FACT[s] * FACT[m - n + s] * FACT[l - m - s]);
    if ((m - n + s) & 1) coef = -coef;
    out += coef * p;
    p *= r;
  }
  return pref * out;
}

// ---------------- K0: all transform constants (fp64 -> fp32) ----------------
// WD [NSX][NJI]  : beta-quadrature-weighted d^l_{m,0}(beta_j) * (2pi/64)
// YK [NS][KG]    : SCALING * d^l_{m,0}(gb_k) * e^{-i m ga_k}
// Dq [NQ][32][16]: (2l+1) * d^l_{m,n}(beta'_j), dense per (m,n)-pair q, 0 for l<lmin
__global__ __launch_bounds__(256) void k_const(float* __restrict__ WD,
                                               float2* __restrict__ YK,
                                               float* __restrict__ Dq) {
  int idx = blockIdx.x * 256 + threadIdx.x;
  if (idx < NSX * NJI) {
    int sx = idx / NJI, j = idx % NJI;
    int l = 0; while ((l + 1) * (l + 2) / 2 <= sx) ++l;
    int m = sx - l * (l + 1) / 2;
    double beta = (j + 0.5) * M_PI / NJI;
    double s = 0.0;
    for (int k = 0; k < 32; ++k)
      s += sin((2.0 * j + 1.0) * (2.0 * k + 1.0) * M_PI / 128.0) / (2.0 * k + 1.0);
    double w = (2.0 / 32.0) * sin(beta) * s * (2.0 * M_PI / 64.0);
    WD[sx * NJI + j] = (float)(w * wig_d(l, m, 0, beta));
    return;
  }
  idx -= NSX * NJI;
  if (idx < NS * KG) {
    int sidx = idx / KG, k = idx % KG;
    int l = 0; while ((l + 1) * (l + 1) <= sidx) ++l;
    int m = sidx - l * l - l;                       // signed m
    double gb = (double)(k / 8 + 1) * (M_PI / 8.0) / 3.0;
    double ga = (double)(k % 8) * (2.0 * M_PI / 8.0);
    double d = wig_d(l, m, 0, gb) * SCALING;
    double sn, c; sincos((double)m * ga, &sn, &c);
    YK[sidx * KG + k] = make_float2((float)(d * c), (float)(-d * sn)); // e^{-i m a}
    return;
  }
  idx -= NS * KG;
  if (idx < NQ * 32 * 16) {
    int q = idx >> 9;                // /512
    int j = (idx >> 4) & 31;
    int l = idx & 15;
    int m = q / 31, n = q % 31 - 15;
    int an = n < 0 ? -n : n;
    int lmin = m > an ? m : an;
    float v = 0.f;
    if (l >= lmin) {
      double beta = (j + 0.5) * M_PI / NJO;
      v = (float)((2 * l + 1) * wig_d(l, m, n, beta));
    }
    Dq[idx] = v;
  }
}

// ---------------- K1: S2 forward transform ----------------
__global__ __launch_bounds__(256) void k_s2fft(const float* __restrict__ x,
                                               const float* __restrict__ WD,
                                               float2* __restrict__ X) {
  __shared__ float  xl[NJI * NJI];   // [j][a] 16 KB
  __shared__ float2 tw[NJI];
  __shared__ float2 xf[NJI * 16];    // [j][m] 8 KB
  __shared__ float2 fx[NSX];
  int t = threadIdx.x;
  int b = blockIdx.x >> 6, f = blockIdx.x & 63;
  const float* xp = x + (size_t)(b * FI + f) * (NJI * NJI);
  for (int r = 0; r < 16; ++r) xl[t + 256 * r] = xp[t + 256 * r];
  if (t < NJI) {
    double s_, c_; sincos(2.0 * M_PI * t / NJI, &s_, &c_);
    tw[t] = make_float2((float)c_, (float)s_);
  }
  __syncthreads();
  for (int r = 0; r < 4; ++r) {
    int oi = t + 256 * r;            // oi = j*16 + m
    int j = oi >> 4, m = oi & 15;
    float re = 0.f, im = 0.f;
    const float* row = xl + j * NJI;
    for (int a = 0; a < NJI; ++a) {
      float2 w = tw[(m * a) & 63];
      float v = row[a];
      re += v * w.x; im -= v * w.y;  // e^{-2pi i m a / 64}
    }
    xf[oi] = make_float2(re, im);
  }
  __syncthreads();
  if (t < NSX) {
    int l = 0; while ((l + 1) * (l + 2) / 2 <= t) ++l;
    int m = t - l * (l + 1) / 2;
    float re = 0.f, im = 0.f;
    const float* wrow = WD + t * NJI;
    for (int j = 0; j < NJI; ++j) {
      float wv = wrow[j];
      float2 v = xf[j * 16 + m];
      re += wv * v.x; im += wv * v.y;
    }
    fx[t] = make_float2(re, im);
  }
  __syncthreads();
  {
    int l = t >> 4, m = t & 15;
    float2 v = make_float2(0.f, 0.f);
    if (m <= l) v = fx[l * (l + 1) / 2 + m];
    X[((size_t)t * NB + b) * FI + f] = v;           // row t = l*16+m (padded)
  }
}

// ---------------- K2: kernel spherical transform ----------------
__global__ __launch_bounds__(256) void k_ytrans(const float* __restrict__ kern,
                                                const float2* __restrict__ YK,
                                                float2* __restrict__ Y) {
  __shared__ float  kl[FO][KG + 1];
  __shared__ float2 ykl[32][KG];
  int t = threadIdx.x;
  int i = blockIdx.x & 63, st = blockIdx.x >> 6;   // s-tile of 32
  int s0 = st * 32;
  for (int r = 0; r < 12; ++r) {
    int fid = t + 256 * r;                          // 3072 floats
    kl[fid / KG][fid % KG] = kern[(size_t)i * FO * KG + fid];
  }
  for (int r = 0; r < 3; ++r) {
    int fid = t + 256 * r;                          // 768 float2
    ykl[fid / KG][fid % KG] = YK[(s0 + fid / KG) * KG + fid % KG];
  }
  __syncthreads();
  int o = t & 127, sh = t >> 7;
  float kr[KG];
  #pragma unroll
  for (int k = 0; k < KG; ++k) kr[k] = kl[o][k];
  for (int ss = sh; ss < 32; ss += 2) {
    float re = 0.f, im = 0.f;
    #pragma unroll
    for (int k = 0; k < KG; ++k) {
      float2 yv = ykl[ss][k];
      re += kr[k] * yv.x; im += kr[k] * yv.y;
    }
    Y[((size_t)(s0 + ss) * FI + i) * FO + o] = make_float2(re, im);
  }
}

// ---------------- K3: block-diagonal spectral matmul ----------------
// Z layout NOW [zidx][bo], bo = b*FO+o  (bo-contiguous for the synthesis GEMMs)
__global__ __launch_bounds__(256) void k_zmm(const float2* __restrict__ X,
                                             const float2* __restrict__ Y,
                                             float2* __restrict__ Z) {
  __shared__ float2 xs[256 * 16];    // [row=l*16+m][ii] 32 KB
  int t = threadIdx.x;
  int b  = blockIdx.x >> 6;
  int ot = (blockIdx.x >> 4) & 3;
  int st = blockIdx.x & 15;          // s-tile of 16
  int s0 = st * 16;
  int o  = ot * 32 + (t & 31);
  int sg = t >> 5;                   // 0..7
  int sq[2] = { s0 + sg, s0 + sg + 8 };
  int lq[2], nq[2];
  #pragma unroll
  for (int q = 0; q < 2; ++q) {
    int s = sq[q];
    int l = 0; while ((l + 1) * (l + 1) <= s) ++l;
    lq[q] = l; nq[q] = s - l * l;    // = n + l
  }
  float2 acc[2][16];
  #pragma unroll
  for (int q = 0; q < 2; ++q)
    #pragma unroll
    for (int m = 0; m < 16; ++m) acc[q][m] = make_float2(0.f, 0.f);

  for (int ic = 0; ic < 4; ++ic) {
    __syncthreads();
    for (int r = 0; r < 16; ++r) {
      int fid = t + 256 * r;         // 4096 float2
      int row = fid >> 4, ii = fid & 15;
      xs[fid] = X[((size_t)row * NB + b) * FI + ic * 16 + ii];
    }
    __syncthreads();
    for (int ii = 0; ii < 16; ++ii) {
      int i = ic * 16 + ii;
      #pragma unroll
      for (int q = 0; q < 2; ++q) {
        float2 yv = Y[((size_t)sq[q] * FI + i) * FO + o];
        const float2* xrow = xs + (lq[q] * 16) * 16 + ii;
        #pragma unroll
        for (int m = 0; m < 16; ++m) {
          float2 xv = xrow[m * 16];
          acc[q][m].x += xv.x * yv.x + xv.y * yv.y;   // X * conj(Y)
          acc[q][m].y += xv.y * yv.x - xv.x * yv.y;
        }
      }
    }
  }
  int bo = b * FO + o;
  for (int q = 0; q < 2; ++q) {
    int l = lq[q];
    for (int m = 0; m <= l; ++m) {
      int zidx = BASE[l] + m * (2 * l + 1) + nq[q];
      Z[(size_t)zidx * NBO + bo] = acc[q][m];
    }
  }
}

// ---------------- K4a: T contraction (streaming, no LDS) ----------------
// T[q][jrel][bo] = sum_{l>=lmin} Dq[q][j][l] * Z[zidx(l,q)][bo]
// grid (NQ, 8 bo-tiles of 128, jc/4); thread = (jq = t>>6, bog = t&63)
__global__ __launch_bounds__(256) void k_T(const float2* __restrict__ Z,
                                           const float* __restrict__ Dq,
                                           float2* __restrict__ T,
                                           int j0, int jc) {
  int t = threadIdx.x;
  int q = blockIdx.x;
  int m = q / 31, n = q % 31 - 15;
  int an = n < 0 ? -n : n;
  int lmin = m > an ? m : an;
  int bo = blockIdx.y * 128 + (t & 63);
  int jrel = blockIdx.z * 4 + (t >> 6);
  int j = j0 + jrel;
  const float* dr = Dq + ((size_t)q * 32 + j) * 16;
  float2 a0 = make_float2(0.f, 0.f), a1 = make_float2(0.f, 0.f);
  for (int l = lmin; l < 16; ++l) {
    int idx = BASE[l] + m * (2 * l + 1) + n + l;
    float d = dr[l];                                // uniform across lanes
    float2 z0 = Z[(size_t)idx * NBO + bo];          // 512B coalesced
    float2 z1 = Z[(size_t)idx * NBO + bo + 64];
    a0.x += d * z0.x; a0.y += d * z0.y;
    a1.x += d * z1.x; a1.y += d * z1.y;
  }
  size_t tb = ((size_t)q * jc + jrel) * NBO + bo;
  T[tb] = a0; T[tb + 64] = a1;
}

// ---------------- K4b: fused U + f synthesis (U lives in registers) ----------------
// block = (jrel, bo-tile of 8). Stage T[496 q][jrel][8 bo] to LDS (31 KB, read as
// broadcasts only). Thread (g = t&31, bo = t>>5) holds U[m=0..15] in registers:
//   U[m,g] = sum_n T[m,n] e^{+2pi i n g/32}   (twiddle recurrence, exact start)
//   f[a,g] = Re U[0] + 2 sum_{m>=1} (cos(2pi m a/32) ReU - sin ImU)
__global__ __launch_bounds__(256) void k_Uf(const float2* __restrict__ T,
                                            float* __restrict__ out,
                                            int j0, int jc) {
  __shared__ float2 tt[NQ * 8];      // 31 KB
  __shared__ float2 tws[32];
  int t = threadIdx.x;
  int jrel = blockIdx.x;
  int bt = blockIdx.y;               // 0..127
  for (int r = 0; r < 16; ++r) {
    int fid = t + 256 * r;
    if (fid < NQ * 8) {
      int q = fid >> 3, c = fid & 7;
      tt[fid] = T[((size_t)q * jc + jrel) * NBO + bt * 8 + c];
    }
  }
  if (t < 32) {
    double s_, c_; sincos(2.0 * M_PI * t / 32.0, &s_, &c_);
    tws[t] = make_float2((float)c_, (float)s_);
  }
  __syncthreads();                   // the only barrier
  int g = t & 31, bo = t >> 5;
  float2 U[16];
  #pragma unroll
  for (int m = 0; m < 16; ++m) {     // ns = 0 term
    float2 tv = tt[(m * 31 + 15) * 8 + bo];
    U[m] = tv;
  }
  float2 step = tws[g];
  float2 wp = step;                          // e^{+i g theta}
  float2 wm = make_float2(step.x, -step.y);  // e^{-i g theta}
  for (int k = 1; k <= 15; ++k) {
    #pragma unroll
    for (int m = 0; m < 16; ++m) {
      float2 tp = tt[(m * 31 + 15 + k) * 8 + bo];   // broadcast reads
      float2 tm = tt[(m * 31 + 15 - k) * 8 + bo];
      U[m].x += tp.x * wp.x - tp.y * wp.y + tm.x * wm.x - tm.y * wm.y;
      U[m].y += tp.x * wp.y + tp.y * wp.x + tm.x * wm.y + tm.y * wm.x;
    }
    float2 nwp = make_float2(wp.x * step.x - wp.y * step.y,
                             wp.x * step.y + wp.y * step.x);
    float2 nwm = make_float2(wm.x * step.x + wm.y * step.y,
                             wm.y * step.x - wm.x * step.y);
    wp = nwp; wm = nwm;
  }
  int j = j0 + jrel;
  size_t ob = ((size_t)(bt * 8 + bo) * 32 + j) * 1024;
  for (int a = 0; a < 32; ++a) {
    float val = U[0].x;
    #pragma unroll
    for (int m = 1; m < 16; ++m) {
      float2 wv = tws[(m * a) & 31];
      val += 2.f * (wv.x * U[m].x - wv.y * U[m].y);
    }
    out[ob + a * 32 + g] = val;      // 128B coalesced per a
  }
}

// ---------------- launch ----------------
extern "C" void kernel_launch(void* const* d_in, const int* in_sizes, int n_in,
                              void* d_out, int out_size, void* d_ws, size_t ws_size,
                              hipStream_t stream) {
  (void)in_sizes; (void)n_in; (void)out_size;
  const float* x    = (const float*)d_in[0];
  const float* kern = (const float*)d_in[1];
  float* out = (float*)d_out;
  float* ws  = (float*)d_ws;
  // workspace layout (float offsets, all 8B-aligned)
  float*  WD = ws;                         //      0 : 8704 f
  float2* YK = (float2*)(ws + 8704);       //   8704 : 12288 f
  float*  Dq = ws + 20992;                 //  20992 : 253952 f
  float2* X  = (float2*)(ws + 274944);     // 274944 : 262144 f
  float2* Y  = (float2*)(ws + 537088);     // 537088 : 4194304 f
  float2* Z  = (float2*)(ws + 4731392);    // 4731392: 5849088 f -> end 10580480 (42.3 MB)
  const size_t FIXED_END = 10580480;
  const size_t T_PER_J   = 1015808;        // 496*1024*2 floats per j
  size_t availf = ws_size / 4;
  int jc; size_t Toff;
  if      (availf >= FIXED_END + T_PER_J * 32) { jc = 32; Toff = FIXED_END; }
  else if (availf >= FIXED_END + T_PER_J * 16) { jc = 16; Toff = FIXED_END; }
  else if (availf >= FIXED_END + T_PER_J * 8)  { jc = 8;  Toff = FIXED_END; }
  else if (availf >= FIXED_END + T_PER_J * 4)  { jc = 4;  Toff = FIXED_END; }
  else { jc = 4; Toff = 274944; }          // overlap X+Y (dead after k_zmm): 4.46M f >= 4.06M f
  float2* Tb = (float2*)(ws + Toff);

  hipLaunchKernelGGL(k_const,  dim3(1050), dim3(256), 0, stream, WD, YK, Dq);
  hipLaunchKernelGGL(k_s2fft,  dim3(512),  dim3(256), 0, stream, x, WD, X);
  hipLaunchKernelGGL(k_ytrans, dim3(512),  dim3(256), 0, stream, kern, YK, Y);
  hipLaunchKernelGGL(k_zmm,    dim3(512),  dim3(256), 0, stream, X, Y, Z);
  for (int j0 = 0; j0 < 32; j0 += jc) {
    hipLaunchKernelGGL(k_T,  dim3(NQ, 8, jc / 4), dim3(256), 0, stream, Z, Dq, Tb, j0, jc);
    hipLaunchKernelGGL(k_Uf, dim3(jc, 128),       dim3(256), 0, stream, Tb, out, j0, jc);
  }
}

// Round 8
// 430.083 us; speedup vs baseline: 2.4583x; 1.1595x over previous
//
#include <hip/hip_runtime.h>
#include <math.h>

// ---------------- problem constants ----------------
#define NLD 16      // degrees l = 0..15
#define NSX 136     // # (l, m>=0) pairs = sum(l+1)
#define NS  256     // # (l, m) pairs full = NL^2
#define KG  24      // kernel grid points
#define FI  64
#define FO  128
#define NB  8
#define NJI 64      // 2*B_IN
#define NJO 32      // 2*B_OUT
#define NZ  2856    // # (l, m>=0, n) triples = sum (l+1)(2l+1)
#define NQ  496     // # (m>=0, n) pairs = 16*31
#define NBO 1024    // B*FO
#define SCALING 0.07216878364870323  // 1/sqrt(24*64*16^3/32^3) = 1/sqrt(192)

// base offset of degree l in the (l,m>=0,n) l-major packing
__device__ const int BASE[17] = {0,1,7,22,50,95,161,252,372,525,715,946,
                                 1222,1547,1925,2360,2856};

__device__ const double FACT[33] = {
  1.0,1.0,2.0,6.0,24.0,120.0,720.0,5040.0,40320.0,362880.0,3628800.0,
  39916800.0,479001600.0,6227020800.0,87178291200.0,1307674368000.0,
  20922789888000.0,355687428096000.0,6402373705728000.0,121645100408832000.0,
  2432902008176640000.0,51090942171709440000.0,1124000727777607680000.0,
  25852016738884976640000.0,620448401733239439360000.0,
  15511210043330985984000000.0,403291461126605635584000000.0,
  10888869450418352160768000000.0,304888344611713860501504000000.0,
  8841761993739701954543616000000.0,265252859812191058636308480000000.0,
  8222838654177922817725562880000000.0,263130836933693530167218012160000000.0};

// Wigner small-d d^l_{m,n}(beta), double precision, matches reference formula
__device__ double wig_d(int l, int m, int n, double beta) {
  double cb = cos(0.5 * beta), sb = sin(0.5 * beta);
  int smin = max(0, n - m), smax = min(l + n, l - m);
  double pref = sqrt(FACT[l + m] * FACT[l - m] * FACT[l + n] * FACT[l - n]);
  int ec = 2 * l + n - m - 2 * smin;   // >= 0
  int es = m - n + 2 * smin;           // >= 0
  double p = 1.0;
  for (int t = 0; t < ec; ++t) p *= cb;
  for (int t = 0; t < es; ++t) p *= sb;
  double r = (sb * sb) / (cb * cb);
  double out = 0.0;
  for (int s = smin; s <= smax; ++s) {
    double coef = 1.0 / (FACT[l + n - s] * FACT[s] * FACT[m - n + s] * FACT[l - m - s]);
    if ((m - n + s) & 1) coef = -coef;
    out += coef * p;
    p *= r;
  }
  return pref * out;
}

// ---------------- K0: all transform constants (fp64 -> fp32) ----------------
// WD [NSX][NJI]  : beta-quadrature-weighted d^l_{m,0}(beta_j) * (2pi/64)
// YK [NS][KG]    : SCALING * d^l_{m,0}(gb_k) * e^{-i m ga_k}
// Dq [NQ][32][16]: (2l+1) * d^l_{m,n}(beta'_j), dense per (m,n)-pair q, 0 for l<lmin
__global__ __launch_bounds__(256) void k_const(float* __restrict__ WD,
                                               float2* __restrict__ YK,
                                               float* __restrict__ Dq) {
  int idx = blockIdx.x * 256 + threadIdx.x;
  if (idx < NSX * NJI) {
    int sx = idx / NJI, j = idx % NJI;
    int l = 0; while ((l + 1) * (l + 2) / 2 <= sx) ++l;
    int m = sx - l * (l + 1) / 2;
    double beta = (j + 0.5) * M_PI / NJI;
    double s = 0.0;
    for (int k = 0; k < 32; ++k)
      s += sin((2.0 * j + 1.0) * (2.0 * k + 1.0) * M_PI / 128.0) / (2.0 * k + 1.0);
    double w = (2.0 / 32.0) * sin(beta) * s * (2.0 * M_PI / 64.0);
    WD[sx * NJI + j] = (float)(w * wig_d(l, m, 0, beta));
    return;
  }
  idx -= NSX * NJI;
  if (idx < NS * KG) {
    int sidx = idx / KG, k = idx % KG;
    int l = 0; while ((l + 1) * (l + 1) <= sidx) ++l;
    int m = sidx - l * l - l;                       // signed m
    double gb = (double)(k / 8 + 1) * (M_PI / 8.0) / 3.0;
    double ga = (double)(k % 8) * (2.0 * M_PI / 8.0);
    double d = wig_d(l, m, 0, gb) * SCALING;
    double sn, c; sincos((double)m * ga, &sn, &c);
    YK[sidx * KG + k] = make_float2((float)(d * c), (float)(-d * sn)); // e^{-i m a}
    return;
  }
  idx -= NS * KG;
  if (idx < NQ * 32 * 16) {
    int q = idx >> 9;                // /512
    int j = (idx >> 4) & 31;
    int l = idx & 15;
    int m = q / 31, n = q % 31 - 15;
    int an = n < 0 ? -n : n;
    int lmin = m > an ? m : an;
    float v = 0.f;
    if (l >= lmin) {
      double beta = (j + 0.5) * M_PI / NJO;
      v = (float)((2 * l + 1) * wig_d(l, m, n, beta));
    }
    Dq[idx] = v;
  }
}

// ---------------- K1: S2 forward transform ----------------
__global__ __launch_bounds__(256) void k_s2fft(const float* __restrict__ x,
                                               const float* __restrict__ WD,
                                               float2* __restrict__ X) {
  __shared__ float  xl[NJI * NJI];   // [j][a] 16 KB
  __shared__ float2 tw[NJI];
  __shared__ float2 xf[NJI * 16];    // [j][m] 8 KB
  __shared__ float2 fx[NSX];
  int t = threadIdx.x;
  int b = blockIdx.x >> 6, f = blockIdx.x & 63;
  const float* xp = x + (size_t)(b * FI + f) * (NJI * NJI);
  for (int r = 0; r < 16; ++r) xl[t + 256 * r] = xp[t + 256 * r];
  if (t < NJI) {
    double s_, c_; sincos(2.0 * M_PI * t / NJI, &s_, &c_);
    tw[t] = make_float2((float)c_, (float)s_);
  }
  __syncthreads();
  for (int r = 0; r < 4; ++r) {
    int oi = t + 256 * r;            // oi = j*16 + m
    int j = oi >> 4, m = oi & 15;
    float re = 0.f, im = 0.f;
    const float* row = xl + j * NJI;
    for (int a = 0; a < NJI; ++a) {
      float2 w = tw[(m * a) & 63];
      float v = row[a];
      re += v * w.x; im -= v * w.y;  // e^{-2pi i m a / 64}
    }
    xf[oi] = make_float2(re, im);
  }
  __syncthreads();
  if (t < NSX) {
    int l = 0; while ((l + 1) * (l + 2) / 2 <= t) ++l;
    int m = t - l * (l + 1) / 2;
    float re = 0.f, im = 0.f;
    const float* wrow = WD + t * NJI;
    for (int j = 0; j < NJI; ++j) {
      float wv = wrow[j];
      float2 v = xf[j * 16 + m];
      re += wv * v.x; im += wv * v.y;
    }
    fx[t] = make_float2(re, im);
  }
  __syncthreads();
  {
    int l = t >> 4, m = t & 15;
    float2 v = make_float2(0.f, 0.f);
    if (m <= l) v = fx[l * (l + 1) / 2 + m];
    X[((size_t)t * NB + b) * FI + f] = v;           // row t = l*16+m (padded)
  }
}

// ---------------- K2: kernel spherical transform ----------------
__global__ __launch_bounds__(256) void k_ytrans(const float* __restrict__ kern,
                                                const float2* __restrict__ YK,
                                                float2* __restrict__ Y) {
  __shared__ float  kl[FO][KG + 1];
  __shared__ float2 ykl[32][KG];
  int t = threadIdx.x;
  int i = blockIdx.x & 63, st = blockIdx.x >> 6;   // s-tile of 32
  int s0 = st * 32;
  for (int r = 0; r < 12; ++r) {
    int fid = t + 256 * r;                          // 3072 floats
    kl[fid / KG][fid % KG] = kern[(size_t)i * FO * KG + fid];
  }
  for (int r = 0; r < 3; ++r) {
    int fid = t + 256 * r;                          // 768 float2
    ykl[fid / KG][fid % KG] = YK[(s0 + fid / KG) * KG + fid % KG];
  }
  __syncthreads();
  int o = t & 127, sh = t >> 7;
  float kr[KG];
  #pragma unroll
  for (int k = 0; k < KG; ++k) kr[k] = kl[o][k];
  for (int ss = sh; ss < 32; ss += 2) {
    float re = 0.f, im = 0.f;
    #pragma unroll
    for (int k = 0; k < KG; ++k) {
      float2 yv = ykl[ss][k];
      re += kr[k] * yv.x; im += kr[k] * yv.y;
    }
    Y[((size_t)(s0 + ss) * FI + i) * FO + o] = make_float2(re, im);
  }
}

// ---------------- K3: block-diagonal spectral matmul ----------------
// Z layout [zidx][bo], bo = b*FO+o  (bo-contiguous for the synthesis GEMMs)
__global__ __launch_bounds__(256) void k_zmm(const float2* __restrict__ X,
                                             const float2* __restrict__ Y,
                                             float2* __restrict__ Z) {
  __shared__ float2 xs[256 * 16];    // [row=l*16+m][ii] 32 KB
  int t = threadIdx.x;
  int b  = blockIdx.x >> 6;
  int ot = (blockIdx.x >> 4) & 3;
  int st = blockIdx.x & 15;          // s-tile of 16
  int s0 = st * 16;
  int o  = ot * 32 + (t & 31);
  int sg = t >> 5;                   // 0..7
  int sq[2] = { s0 + sg, s0 + sg + 8 };
  int lq[2], nq[2];
  #pragma unroll
  for (int q = 0; q < 2; ++q) {
    int s = sq[q];
    int l = 0; while ((l + 1) * (l + 1) <= s) ++l;
    lq[q] = l; nq[q] = s - l * l;    // = n + l
  }
  float2 acc[2][16];
  #pragma unroll
  for (int q = 0; q < 2; ++q)
    #pragma unroll
    for (int m = 0; m < 16; ++m) acc[q][m] = make_float2(0.f, 0.f);

  for (int ic = 0; ic < 4; ++ic) {
    __syncthreads();
    for (int r = 0; r < 16; ++r) {
      int fid = t + 256 * r;         // 4096 float2
      int row = fid >> 4, ii = fid & 15;
      xs[fid] = X[((size_t)row * NB + b) * FI + ic * 16 + ii];
    }
    __syncthreads();
    for (int ii = 0; ii < 16; ++ii) {
      int i = ic * 16 + ii;
      #pragma unroll
      for (int q = 0; q < 2; ++q) {
        float2 yv = Y[((size_t)sq[q] * FI + i) * FO + o];
        const float2* xrow = xs + (lq[q] * 16) * 16 + ii;
        #pragma unroll
        for (int m = 0; m < 16; ++m) {
          float2 xv = xrow[m * 16];
          acc[q][m].x += xv.x * yv.x + xv.y * yv.y;   // X * conj(Y)
          acc[q][m].y += xv.y * yv.x - xv.x * yv.y;
        }
      }
    }
  }
  int bo = b * FO + o;
  for (int q = 0; q < 2; ++q) {
    int l = lq[q];
    for (int m = 0; m <= l; ++m) {
      int zidx = BASE[l] + m * (2 * l + 1) + nq[q];
      Z[(size_t)zidx * NBO + bo] = acc[q][m];
    }
  }
}

// ---------------- K4a: T contraction (streaming, no LDS) ----------------
// T[q][jrel][bo] = sum_{l>=lmin} Dq[q][j][l] * Z[zidx(l,q)][bo]
__global__ __launch_bounds__(256) void k_T(const float2* __restrict__ Z,
                                           const float* __restrict__ Dq,
                                           float2* __restrict__ T,
                                           int j0, int jc) {
  int t = threadIdx.x;
  int q = blockIdx.x;
  int m = q / 31, n = q % 31 - 15;
  int an = n < 0 ? -n : n;
  int lmin = m > an ? m : an;
  int bo = blockIdx.y * 128 + (t & 63);
  int jrel = blockIdx.z * 4 + (t >> 6);
  int j = j0 + jrel;
  const float* dr = Dq + ((size_t)q * 32 + j) * 16;
  float2 a0 = make_float2(0.f, 0.f), a1 = make_float2(0.f, 0.f);
  for (int l = lmin; l < 16; ++l) {
    int idx = BASE[l] + m * (2 * l + 1) + n + l;
    float d = dr[l];                                // uniform across lanes
    float2 z0 = Z[(size_t)idx * NBO + bo];          // 512B coalesced
    float2 z1 = Z[(size_t)idx * NBO + bo + 64];
    a0.x += d * z0.x; a0.y += d * z0.y;
    a1.x += d * z1.x; a1.y += d * z1.y;
  }
  size_t tb = ((size_t)q * jc + jrel) * NBO + bo;
  T[tb] = a0; T[tb + 64] = a1;
}

// ---------------- K4b: fused U + f synthesis v2 (g-paired, a-folded) ----------------
// block = 128 threads: (g = t&15 -> handles g and g+16) x (bo = t>>4, 8 bo).
// Symmetries on the 32-point grid (theta = 2pi/32):
//   e^{in(g+16)theta} = (-1)^n e^{ing theta}; for n=+-k both get (-1)^k, so
//   c_k = T(+k)*wp + T(-k)*wm feeds U[g] += c_k and U[g+16] += (-1)^k c_k
//   (shared LDS reads + complex core).
//   e^{im(a+16)theta} = (-1)^m e^{ima theta}: even/odd-m split E,O gives
//   f[a]=E+O, f[a+16]=E-O.
__global__ __launch_bounds__(128) void k_Uf(const float2* __restrict__ T,
                                            float* __restrict__ out,
                                            int j0, int jc) {
  __shared__ float2 tt[NQ * 8];      // 31 KB
  __shared__ float2 tws[32];
  int t = threadIdx.x;
  int jrel = blockIdx.x;
  int bt = blockIdx.y;               // 0..127
  for (int r = 0; r < 31; ++r) {     // 128*31 = 3968 = NQ*8 exactly
    int fid = t + 128 * r;
    int q = fid >> 3, c = fid & 7;
    tt[fid] = T[((size_t)q * jc + jrel) * NBO + bt * 8 + c];
  }
  if (t < 32) {
    double s_, c_; sincos(2.0 * M_PI * t / 32.0, &s_, &c_);
    tws[t] = make_float2((float)c_, (float)s_);
  }
  __syncthreads();                   // the only barrier
  int g = t & 15, bo = t >> 4;
  float2 U0[16], U1[16];             // U[m] for g and g+16
  #pragma unroll
  for (int m = 0; m < 16; ++m) {     // n = 0 term (same for both g's)
    float2 tv = tt[(m * 31 + 15) * 8 + bo];
    U0[m] = tv; U1[m] = tv;
  }
  float2 step = tws[g];
  float2 wp = step;                          // e^{+i g k theta}
  float2 wm = make_float2(step.x, -step.y);  // e^{-i g k theta}
  #pragma unroll
  for (int k = 1; k <= 15; ++k) {
    const float sgn = (k & 1) ? -1.f : 1.f;  // (-1)^k
    #pragma unroll
    for (int m = 0; m < 16; ++m) {
      float2 tp = tt[(m * 31 + 15 + k) * 8 + bo];   // broadcast reads
      float2 tm = tt[(m * 31 + 15 - k) * 8 + bo];
      float cx = tp.x * wp.x - tp.y * wp.y + tm.x * wm.x - tm.y * wm.y;
      float cy = tp.x * wp.y + tp.y * wp.x + tm.x * wm.y + tm.y * wm.x;
      U0[m].x += cx;        U0[m].y += cy;
      U1[m].x += sgn * cx;  U1[m].y += sgn * cy;
    }
    float2 nwp = make_float2(wp.x * step.x - wp.y * step.y,
                             wp.x * step.y + wp.y * step.x);
    float2 nwm = make_float2(wm.x * step.x + wm.y * step.y,
                             wm.y * step.x - wm.x * step.y);
    wp = nwp; wm = nwm;
  }
  #pragma unroll
  for (int m = 1; m < 16; ++m) {     // fold the 2x Hermitian factor into U
    U0[m].x *= 2.f; U0[m].y *= 2.f;
    U1[m].x *= 2.f; U1[m].y *= 2.f;
  }
  int j = j0 + jrel;
  size_t ob = ((size_t)(bt * 8 + bo) * 32 + j) * 1024;
  for (int a = 0; a < 16; ++a) {
    float e0 = U0[0].x, o0 = 0.f;    // even/odd-m partial sums, g
    float e1 = U1[0].x, o1 = 0.f;    // and g+16
    #pragma unroll
    for (int m = 1; m < 16; ++m) {
      float2 wv = tws[(m * a) & 31];
      float v0 = wv.x * U0[m].x - wv.y * U0[m].y;
      float v1 = wv.x * U1[m].x - wv.y * U1[m].y;
      if (m & 1) { o0 += v0; o1 += v1; } else { e0 += v0; e1 += v1; }
    }
    out[ob + a * 32 + g]             = e0 + o0;
    out[ob + a * 32 + g + 16]        = e1 + o1;
    out[ob + (a + 16) * 32 + g]      = e0 - o0;
    out[ob + (a + 16) * 32 + g + 16] = e1 - o1;
  }
}

// ---------------- launch ----------------
extern "C" void kernel_launch(void* const* d_in, const int* in_sizes, int n_in,
                              void* d_out, int out_size, void* d_ws, size_t ws_size,
                              hipStream_t stream) {
  (void)in_sizes; (void)n_in; (void)out_size;
  const float* x    = (const float*)d_in[0];
  const float* kern = (const float*)d_in[1];
  float* out = (float*)d_out;
  float* ws  = (float*)d_ws;
  // workspace layout (float offsets, all 8B-aligned)
  float*  WD = ws;                         //      0 : 8704 f
  float2* YK = (float2*)(ws + 8704);       //   8704 : 12288 f
  float*  Dq = ws + 20992;                 //  20992 : 253952 f
  float2* X  = (float2*)(ws + 274944);     // 274944 : 262144 f
  float2* Y  = (float2*)(ws + 537088);     // 537088 : 4194304 f
  float2* Z  = (float2*)(ws + 4731392);    // 4731392: 5849088 f -> end 10580480 (42.3 MB)
  const size_t FIXED_END = 10580480;
  const size_t T_PER_J   = 1015808;        // 496*1024*2 floats per j
  size_t availf = ws_size / 4;
  int jc; size_t Toff;
  if      (availf >= FIXED_END + T_PER_J * 32) { jc = 32; Toff = FIXED_END; }
  else if (availf >= FIXED_END + T_PER_J * 16) { jc = 16; Toff = FIXED_END; }
  else if (availf >= FIXED_END + T_PER_J * 8)  { jc = 8;  Toff = FIXED_END; }
  else if (availf >= FIXED_END + T_PER_J * 4)  { jc = 4;  Toff = FIXED_END; }
  else { jc = 4; Toff = 274944; }          // overlap X+Y (dead after k_zmm): 4.46M f >= 4.06M f
  float2* Tb = (float2*)(ws + Toff);

  hipLaunchKernelGGL(k_const,  dim3(1050), dim3(256), 0, stream, WD, YK, Dq);
  hipLaunchKernelGGL(k_s2fft,  dim3(512),  dim3(256), 0, stream, x, WD, X);
  hipLaunchKernelGGL(k_ytrans, dim3(512),  dim3(256), 0, stream, kern, YK, Y);
  hipLaunchKernelGGL(k_zmm,    dim3(512),  dim3(256), 0, stream, X, Y, Z);
  for (int j0 = 0; j0 < 32; j0 += jc) {
    hipLaunchKernelGGL(k_T,  dim3(NQ, 8, jc / 4), dim3(256), 0, stream, Z, Dq, Tb, j0, jc);
    hipLaunchKernelGGL(k_Uf, dim3(jc, 128),       dim3(128), 0, stream, Tb, out, j0, jc);
  }
}